// Round 5
// baseline (21279.901 us; speedup 1.0000x reference)
//
#include <hip/hip_runtime.h>
#include <hip/hip_bf16.h>
#include <stdint.h>

// Problem constants
#define HD   1024
#define BB   32
#define TT   512
#define LL   3
#define H3   3072
#define MTOT (BB*TT)   // 16384

typedef unsigned short u16;
typedef short bf16x8 __attribute__((ext_vector_type(8)));
typedef float f32x4 __attribute__((ext_vector_type(4)));

__device__ __forceinline__ u16 f2bf_bits(float f) {
    __hip_bfloat16 h = __float2bfloat16(f);   // RNE
    return __builtin_bit_cast(u16, h);
}
__device__ __forceinline__ float bf_bits2f(u16 b) {
    return __bfloat162float(__builtin_bit_cast(__hip_bfloat16, b));
}

// ---- coherent (IC-level) loads: sc0 sc1 bypasses L1 and per-XCD L2.
__device__ __forceinline__ void coh_load_f4(f32x4& d, const float* p) {
    asm volatile("global_load_dwordx4 %0, %1, off sc0 sc1" : "=v"(d) : "v"(p));
}
__device__ __forceinline__ void ld_u16_async(unsigned& d, const u16* p) {
    asm volatile("global_load_ushort %0, %1, off" : "=v"(d) : "v"(p));
}

// ---------------------------------------------------------------------------
// Split fp32 -> (hi, lo) bf16 planes
__global__ void split_f32_kernel(const float* __restrict__ in,
                                 u16* __restrict__ hi, u16* __restrict__ lo, int n4) {
    int i = blockIdx.x * blockDim.x + threadIdx.x;
    int stride = gridDim.x * blockDim.x;
    for (; i < n4; i += stride) {
        float4 v = ((const float4*)in)[i];
        ushort4 h, l;
        float f;
        f = v.x; h.x = f2bf_bits(f); l.x = f2bf_bits(f - bf_bits2f(h.x));
        f = v.y; h.y = f2bf_bits(f); l.y = f2bf_bits(f - bf_bits2f(h.y));
        f = v.z; h.z = f2bf_bits(f); l.z = f2bf_bits(f - bf_bits2f(h.z));
        f = v.w; h.w = f2bf_bits(f); l.w = f2bf_bits(f - bf_bits2f(h.w));
        ((ushort4*)hi)[i] = h;
        ((ushort4*)lo)[i] = l;
    }
}

// fp32 -> bf16 (hi only)
__global__ void tobf_kernel(const float* __restrict__ in, u16* __restrict__ out, int n4) {
    int i = blockIdx.x * blockDim.x + threadIdx.x;
    int stride = gridDim.x * blockDim.x;
    for (; i < n4; i += stride) {
        float4 v = ((const float4*)in)[i];
        ushort4 h;
        h.x = f2bf_bits(v.x); h.y = f2bf_bits(v.y);
        h.z = f2bf_bits(v.z); h.w = f2bf_bits(v.w);
        ((ushort4*)out)[i] = h;
    }
}

// ---------------------------------------------------------------------------
// 2-pass split-A bf16 MFMA GEMM:  C[t*32+b][n] = sum_k (Ahi+Alo)[b*512+t][k]*W[n][k] + bias[n]
#define BM 128
#define BN 128
#define BK 32
#define LDSROW 40   // 32 data bf16 + 8 pad

__global__ __launch_bounds__(256) void gemm2p_kernel(
    const u16* __restrict__ Ahi, const u16* __restrict__ Alo,  // [M][1024]
    const u16* __restrict__ Wn,                                 // [3072][1024]
    const float* __restrict__ bias,                             // [3072]
    u16* __restrict__ Cout)                                     // [T*B perm][3072]
{
    __shared__ u16 sAh[BM * LDSROW];
    __shared__ u16 sAl[BM * LDSROW];
    __shared__ u16 sB [BN * LDSROW];

    const int tid  = threadIdx.x;
    const int lane = tid & 63;
    const int w    = tid >> 6;        // 4 waves
    const int wr   = w >> 1, wc = w & 1;
    const int fr   = lane & 15;
    const int kg   = lane >> 4;

    const int bm = blockIdx.x & 127;         // M/BM = 128
    const int bn = blockIdx.x >> 7;          // N/BN = 24
    const int bmBase = bm * BM;
    const int bnBase = bn * BN;

    f32x4 acc[4][4] = {};

    for (int kt = 0; kt < 1024; kt += BK) {
        uint4 ra[2], rl[2], rb[2];
#pragma unroll
        for (int it = 0; it < 2; ++it) {
            int c = it * 256 + tid;
            int row = c >> 2, seg = c & 3;
            size_t ga = (size_t)(bmBase + row) * 1024 + kt + seg * 8;
            ra[it] = *(const uint4*)(Ahi + ga);
            rl[it] = *(const uint4*)(Alo + ga);
            size_t gb = (size_t)(bnBase + row) * 1024 + kt + seg * 8;
            rb[it] = *(const uint4*)(Wn + gb);
        }
        __syncthreads();
#pragma unroll
        for (int it = 0; it < 2; ++it) {
            int c = it * 256 + tid;
            int row = c >> 2, seg = c & 3;
            int lo = row * LDSROW + seg * 8;
            *(uint4*)(sAh + lo) = ra[it];
            *(uint4*)(sAl + lo) = rl[it];
            *(uint4*)(sB  + lo) = rb[it];
        }
        __syncthreads();

        bf16x8 fah[4], fal[4], fb[4];
#pragma unroll
        for (int mi = 0; mi < 4; ++mi) {
            int r = wr * 64 + mi * 16 + fr;
            fah[mi] = *(const bf16x8*)(sAh + r * LDSROW + kg * 8);
            fal[mi] = *(const bf16x8*)(sAl + r * LDSROW + kg * 8);
        }
#pragma unroll
        for (int ni = 0; ni < 4; ++ni) {
            int r = wc * 64 + ni * 16 + fr;
            fb[ni] = *(const bf16x8*)(sB + r * LDSROW + kg * 8);
        }
#pragma unroll
        for (int mi = 0; mi < 4; ++mi)
#pragma unroll
            for (int ni = 0; ni < 4; ++ni) {
                acc[mi][ni] = __builtin_amdgcn_mfma_f32_16x16x32_bf16(fah[mi], fb[ni], acc[mi][ni], 0, 0, 0);
                acc[mi][ni] = __builtin_amdgcn_mfma_f32_16x16x32_bf16(fal[mi], fb[ni], acc[mi][ni], 0, 0, 0);
            }
    }

#pragma unroll
    for (int mi = 0; mi < 4; ++mi)
#pragma unroll
        for (int ni = 0; ni < 4; ++ni) {
            int n = bnBase + wc * 64 + ni * 16 + fr;
            float bv = bias[n];
#pragma unroll
            for (int r = 0; r < 4; ++r) {
                int m = bmBase + wr * 64 + mi * 16 + kg * 4 + r;
                int b_ = m >> 9, t_ = m & 511;           // m = b*512 + t
                Cout[(size_t)(t_ * BB + b_) * H3 + n] = f2bf_bits(acc[mi][ni][r] + bv);
            }
        }
}

// ---------------------------------------------------------------------------
// Persistent recurrent kernel: 256 blocks (64 unit-groups x 4 batch-groups) x
// 512 threads. __launch_bounds__(512, 2): exactly 2 waves/EU (1 block/CU,
// grid == CU count) -> ~256 VGPR budget so wreg[6][16] (96 f32/lane of w_hh)
// stays REGISTER-RESIDENT. At the default budget the compiler spilled it and
// re-read ~196KB/block of weights from scratch every timestep (VGPR_Count=76).
#define RGRID 256

__global__ __launch_bounds__(512, 2) void gru_rec_kernel(
    const float* __restrict__ whh,   // [3072][1024] this layer
    const float* __restrict__ bhh,   // [3072]
    const u16*  __restrict__ gi,     // [T][B][3H] bf16, includes b_ih
    const float* __restrict__ h0,    // [B][H] this layer
    float* __restrict__ hbuf0, float* __restrict__ hbuf1,
    u16*  __restrict__ phi, u16* __restrict__ plo,   // next-layer planes or null
    float* __restrict__ seqout,                      // fp32 [B][T][H] or null
    float* __restrict__ hnout,                       // [B][H]
    unsigned* __restrict__ flags)                    // [4 domains][64 producers]
{
    const int tid  = threadIdx.x;
    const int lane = tid & 63;
    const int w    = tid >> 6;           // 8 waves
    const int ug   = blockIdx.x >> 2;    // 0..63
    const int bg   = blockIdx.x & 3;     // 0..3  (sync domain)
    const int u0   = ug * 16;
    const int b0   = bg * 8;

    unsigned* dom_flags = flags + bg * 64;     // this domain's 64 flags (256B)

    __shared__ __align__(16) float h_lds[8 * HD];        // 32 KB
    __shared__ __align__(16) float dsm[8 * 48 * 4];      // 6 KB partials
    __shared__ float bsh[48];

    // weights: wave w holds block-rows w*6..w*6+5; lane's K-slice = {q*256 + lane*4 + e}
    float wreg[6][16];
#pragma unroll
    for (int j = 0; j < 6; ++j) {
        int r = w * 6 + j;
        int g = r >> 4, uu = r & 15;
        const float* wp = whh + (size_t)(g * HD + u0 + uu) * HD;
#pragma unroll
        for (int q = 0; q < 4; ++q) {
            f32x4 v = *(const f32x4*)(wp + q * 256 + lane * 4);
            wreg[j][q * 4 + 0] = v[0]; wreg[j][q * 4 + 1] = v[1];
            wreg[j][q * 4 + 2] = v[2]; wreg[j][q * 4 + 3] = v[3];
        }
    }
    if (tid < 48) bsh[tid] = bhh[(tid >> 4) * HD + u0 + (tid & 15)];
    __syncthreads();

    const int gb = tid >> 4;    // gate-phase batch (tid<128)
    const int gu = tid & 15;    // gate-phase unit

    // gi prefetch for t=0 (pipelined one step ahead thereafter)
    unsigned gr0, gr1, gr2;
    if (tid < 128) {
        const u16* gp = gi + (size_t)(0 * BB + b0 + gb) * H3 + u0 + gu;
        ld_u16_async(gr0, gp);
        ld_u16_async(gr1, gp + HD);
        ld_u16_async(gr2, gp + 2 * HD);
    }

    for (int t = 0; t < TT; ++t) {
        // ---- wave 0 polls this domain's 64 producer flags; others park at barrier
        if (t > 0 && w == 0) {
            const unsigned* fp = dom_flags + lane;
            unsigned v;
            do {
                asm volatile("global_load_dword %0, %1, off sc0 sc1" : "=v"(v) : "v"(fp));
                asm volatile("s_waitcnt vmcnt(0)" : "+v"(v));
            } while (!__all((int)(v >= (unsigned)t)));
        }
        __syncthreads();

        // ---- stage h(t) for our 8 batches into LDS (IC-coherent loads)
        const float* hsrc = (t == 0) ? (h0 + b0 * HD)
                                     : (((t & 1) ? hbuf1 : hbuf0) + b0 * HD);
        f32x4 s0_, s1_, s2_, s3_;
        coh_load_f4(s0_, hsrc + (0 * 512 + tid) * 4);
        coh_load_f4(s1_, hsrc + (1 * 512 + tid) * 4);
        coh_load_f4(s2_, hsrc + (2 * 512 + tid) * 4);
        coh_load_f4(s3_, hsrc + (3 * 512 + tid) * 4);
        asm volatile("s_waitcnt vmcnt(0)" : "+v"(s0_), "+v"(s1_), "+v"(s2_), "+v"(s3_));
        *(f32x4*)&h_lds[(0 * 512 + tid) * 4] = s0_;
        *(f32x4*)&h_lds[(1 * 512 + tid) * 4] = s1_;
        *(f32x4*)&h_lds[(2 * 512 + tid) * 4] = s2_;
        *(f32x4*)&h_lds[(3 * 512 + tid) * 4] = s3_;
        __syncthreads();

        // ---- dot phase: 6 rows x 8 batches per wave, 16 K-elems per lane
#pragma unroll 2
        for (int b = 0; b < 8; ++b) {
            const float* hr = h_lds + b * HD;
            f32x4 h0v = *(const f32x4*)(hr + 0 * 256 + lane * 4);
            f32x4 h1v = *(const f32x4*)(hr + 1 * 256 + lane * 4);
            f32x4 h2v = *(const f32x4*)(hr + 2 * 256 + lane * 4);
            f32x4 h3v = *(const f32x4*)(hr + 3 * 256 + lane * 4);
#pragma unroll
            for (int j = 0; j < 6; ++j) {
                float a = 0.f;
#pragma unroll
                for (int e = 0; e < 4; ++e) {
                    a = fmaf(wreg[j][e],      h0v[e], a);
                    a = fmaf(wreg[j][4 + e],  h1v[e], a);
                    a = fmaf(wreg[j][8 + e],  h2v[e], a);
                    a = fmaf(wreg[j][12 + e], h3v[e], a);
                }
                a += __shfl_xor(a, 1);
                a += __shfl_xor(a, 2);
                a += __shfl_xor(a, 4);
                a += __shfl_xor(a, 8);
                if ((lane & 15) == 0)
                    dsm[(b * 48 + w * 6 + j) * 4 + (lane >> 4)] = a;
            }
        }
        __syncthreads();

        // ---- gate phase: 128 threads, one (b,u) each
        float* hdst = ((t + 1) & 1) ? hbuf1 : hbuf0;
        float hnew = 0.f;
        int gidx = 0;
        size_t orow = 0;
        if (tid < 128) {
            f32x4 p0 = *(const f32x4*)&dsm[(gb * 48 + 0 * 16 + gu) * 4];
            f32x4 p1 = *(const f32x4*)&dsm[(gb * 48 + 1 * 16 + gu) * 4];
            f32x4 p2 = *(const f32x4*)&dsm[(gb * 48 + 2 * 16 + gu) * 4];
            float dr = p0[0] + p0[1] + p0[2] + p0[3] + bsh[gu];
            float dz = p1[0] + p1[1] + p1[2] + p1[3] + bsh[16 + gu];
            float dn = p2[0] + p2[1] + p2[2] + p2[3] + bsh[32 + gu];
            float ir  = bf_bits2f((u16)gr0);
            float iz  = bf_bits2f((u16)gr1);
            float inn = bf_bits2f((u16)gr2);
            float hp = h_lds[gb * HD + u0 + gu];
            float r = 1.f / (1.f + expf(-(ir + dr)));
            float z = 1.f / (1.f + expf(-(iz + dz)));
            float nn = tanhf(inn + r * dn);
            hnew = (1.f - z) * nn + z * hp;
            gidx = (b0 + gb) * HD + u0 + gu;
            orow = ((size_t)(b0 + gb) * TT + t) * HD + u0 + gu;
            // release payload: device-scope atomic, performed+acked at IC
            (void)__hip_atomic_exchange(hdst + gidx, hnew,
                                        __ATOMIC_RELAXED, __HIP_MEMORY_SCOPE_AGENT);
        }
        __syncthreads();   // implicit vmcnt(0): all producers' h atomics acked
        if (t < TT - 1 && tid == 0)
            (void)__hip_atomic_exchange(dom_flags + ug, (unsigned)(t + 1),
                                        __ATOMIC_RELAXED, __HIP_MEMORY_SCOPE_AGENT);
        // ---- off-critical-path: next-step gi prefetch + output stores
        if (t + 1 < TT && tid < 128) {
            const u16* gp = gi + (size_t)((t + 1) * BB + b0 + gb) * H3 + u0 + gu;
            ld_u16_async(gr0, gp);
            ld_u16_async(gr1, gp + HD);
            ld_u16_async(gr2, gp + 2 * HD);
        }
        if (tid < 128) {
            if (seqout) {
                seqout[orow] = hnew;
            } else {
                u16 hb_ = f2bf_bits(hnew);
                phi[orow] = hb_;
                plo[orow] = f2bf_bits(hnew - bf_bits2f(hb_));
            }
            if (t == TT - 1) hnout[gidx] = hnew;
        }
    }
}

// ---------------------------------------------------------------------------
extern "C" void kernel_launch(void* const* d_in, const int* in_sizes, int n_in,
                              void* d_out, int out_size, void* d_ws, size_t ws_size,
                              hipStream_t stream) {
    const float* x   = (const float*)d_in[0];
    const float* h0  = (const float*)d_in[1];
    const float* wih = (const float*)d_in[2];
    const float* whh = (const float*)d_in[3];
    const float* bih = (const float*)d_in[4];
    const float* bhh = (const float*)d_in[5];
    float* out = (float*)d_out;

    char* ws = (char*)d_ws;
    size_t off = 0;
    auto alloc = [&](size_t bytes) -> void* {
        void* p = ws + off;
        off += (bytes + 255) & ~(size_t)255;
        return p;
    };
    u16* gi   = (u16*)alloc((size_t)MTOT * H3 * 2);        // 96 MB
    u16* p0h  = (u16*)alloc((size_t)MTOT * HD * 2);        // 32 MB
    u16* p0l  = (u16*)alloc((size_t)MTOT * HD * 2);
    u16* p1h  = (u16*)alloc((size_t)MTOT * HD * 2);
    u16* p1l  = (u16*)alloc((size_t)MTOT * HD * 2);
    u16* wihb = (u16*)alloc((size_t)LL * H3 * HD * 2);     // 18 MB
    float* hb0 = (float*)alloc((size_t)BB * HD * 4);
    float* hb1 = (float*)alloc((size_t)BB * HD * 4);
    unsigned* flags = (unsigned*)alloc(LL * 4 * 64 * 4);   // [L][4 dom][64]

    hipMemsetAsync(flags, 0, LL * 4 * 64 * 4, stream);

    split_f32_kernel<<<2048, 256, 0, stream>>>(x, p0h, p0l, MTOT * HD / 4);
    tobf_kernel<<<2048, 256, 0, stream>>>(wih, wihb, LL * H3 * HD / 4);

    float* seqbase = out;                        // [B][T][H]
    float* hnbase  = out + (size_t)BB * TT * HD; // [L][B][H]

    for (int l = 0; l < LL; ++l) {
        const u16* ah = (l == 1) ? p1h : p0h;
        const u16* al = (l == 1) ? p1l : p0l;
        gemm2p_kernel<<<dim3(128 * 24), 256, 0, stream>>>(
            ah, al, wihb + (size_t)l * H3 * HD, bih + (size_t)l * H3, gi);

        u16* oh = (l == 0) ? p1h : p0h;
        u16* ol = (l == 0) ? p1l : p0l;
        gru_rec_kernel<<<RGRID, 512, 0, stream>>>(
            whh + (size_t)l * H3 * HD, bhh + (size_t)l * H3, gi,
            h0 + (size_t)l * BB * HD, hb0, hb1,
            (l < 2) ? oh : (u16*)nullptr, (l < 2) ? ol : (u16*)nullptr,
            (l == 2) ? seqbase : (float*)nullptr,
            hnbase + (size_t)l * BB * HD,
            flags + (size_t)l * 4 * 64);
    }
}

// Round 7
// 18156.483 us; speedup vs baseline: 1.1720x; 1.1720x over previous
//
#include <hip/hip_runtime.h>
#include <hip/hip_bf16.h>
#include <stdint.h>

// Problem constants
#define HD   1024
#define BB   32
#define TT   512
#define LL   3
#define H3   3072
#define MTOT (BB*TT)   // 16384

typedef unsigned short u16;
typedef short bf16x8 __attribute__((ext_vector_type(8)));
typedef float f32x4 __attribute__((ext_vector_type(4)));
typedef int   i32x4 __attribute__((ext_vector_type(4)));

__device__ __forceinline__ u16 f2bf_bits(float f) {
    __hip_bfloat16 h = __float2bfloat16(f);   // RNE
    return __builtin_bit_cast(u16, h);
}
__device__ __forceinline__ float bf_bits2f(u16 b) {
    return __bfloat162float(__builtin_bit_cast(__hip_bfloat16, b));
}

__device__ __forceinline__ void coh_store_u16(u16* p, unsigned v) {
    asm volatile("global_store_short %0, %1, off sc0 sc1" : : "v"(p), "v"(v) : "memory");
}
__device__ __forceinline__ void ld_u16_async(unsigned& d, const u16* p) {
    asm volatile("global_load_ushort %0, %1, off" : "=v"(d) : "v"(p));
}

// ---------------------------------------------------------------------------
// Split fp32 -> (hi, lo) bf16 planes
__global__ void split_f32_kernel(const float* __restrict__ in,
                                 u16* __restrict__ hi, u16* __restrict__ lo, int n4) {
    int i = blockIdx.x * blockDim.x + threadIdx.x;
    int stride = gridDim.x * blockDim.x;
    for (; i < n4; i += stride) {
        float4 v = ((const float4*)in)[i];
        ushort4 h, l;
        float f;
        f = v.x; h.x = f2bf_bits(f); l.x = f2bf_bits(f - bf_bits2f(h.x));
        f = v.y; h.y = f2bf_bits(f); l.y = f2bf_bits(f - bf_bits2f(h.y));
        f = v.z; h.z = f2bf_bits(f); l.z = f2bf_bits(f - bf_bits2f(h.z));
        f = v.w; h.w = f2bf_bits(f); l.w = f2bf_bits(f - bf_bits2f(h.w));
        ((ushort4*)hi)[i] = h;
        ((ushort4*)lo)[i] = l;
    }
}

// fp32 -> bf16 (hi only)
__global__ void tobf_kernel(const float* __restrict__ in, u16* __restrict__ out, int n4) {
    int i = blockIdx.x * blockDim.x + threadIdx.x;
    int stride = gridDim.x * blockDim.x;
    for (; i < n4; i += stride) {
        float4 v = ((const float4*)in)[i];
        ushort4 h;
        h.x = f2bf_bits(v.x); h.y = f2bf_bits(v.y);
        h.z = f2bf_bits(v.z); h.w = f2bf_bits(v.w);
        ((ushort4*)out)[i] = h;
    }
}

// ---------------------------------------------------------------------------
// 2-pass split-A bf16 MFMA GEMM (input projections) — unchanged since R2.
#define BM 128
#define BN 128
#define BK 32
#define LDSROW 40

__global__ __launch_bounds__(256) void gemm2p_kernel(
    const u16* __restrict__ Ahi, const u16* __restrict__ Alo,
    const u16* __restrict__ Wn,
    const float* __restrict__ bias,
    u16* __restrict__ Cout)
{
    __shared__ u16 sAh[BM * LDSROW];
    __shared__ u16 sAl[BM * LDSROW];
    __shared__ u16 sB [BN * LDSROW];

    const int tid  = threadIdx.x;
    const int lane = tid & 63;
    const int w    = tid >> 6;
    const int wr   = w >> 1, wc = w & 1;
    const int fr   = lane & 15;
    const int kg   = lane >> 4;

    const int bm = blockIdx.x & 127;
    const int bn = blockIdx.x >> 7;
    const int bmBase = bm * BM;
    const int bnBase = bn * BN;

    f32x4 acc[4][4] = {};

    for (int kt = 0; kt < 1024; kt += BK) {
        uint4 ra[2], rl[2], rb[2];
#pragma unroll
        for (int it = 0; it < 2; ++it) {
            int c = it * 256 + tid;
            int row = c >> 2, seg = c & 3;
            size_t ga = (size_t)(bmBase + row) * 1024 + kt + seg * 8;
            ra[it] = *(const uint4*)(Ahi + ga);
            rl[it] = *(const uint4*)(Alo + ga);
            size_t gb = (size_t)(bnBase + row) * 1024 + kt + seg * 8;
            rb[it] = *(const uint4*)(Wn + gb);
        }
        __syncthreads();
#pragma unroll
        for (int it = 0; it < 2; ++it) {
            int c = it * 256 + tid;
            int row = c >> 2, seg = c & 3;
            int lo = row * LDSROW + seg * 8;
            *(uint4*)(sAh + lo) = ra[it];
            *(uint4*)(sAl + lo) = rl[it];
            *(uint4*)(sB  + lo) = rb[it];
        }
        __syncthreads();

        bf16x8 fah[4], fal[4], fb[4];
#pragma unroll
        for (int mi = 0; mi < 4; ++mi) {
            int r = wr * 64 + mi * 16 + fr;
            fah[mi] = *(const bf16x8*)(sAh + r * LDSROW + kg * 8);
            fal[mi] = *(const bf16x8*)(sAl + r * LDSROW + kg * 8);
        }
#pragma unroll
        for (int ni = 0; ni < 4; ++ni) {
            int r = wc * 64 + ni * 16 + fr;
            fb[ni] = *(const bf16x8*)(sB + r * LDSROW + kg * 8);
        }
#pragma unroll
        for (int mi = 0; mi < 4; ++mi)
#pragma unroll
            for (int ni = 0; ni < 4; ++ni) {
                acc[mi][ni] = __builtin_amdgcn_mfma_f32_16x16x32_bf16(fah[mi], fb[ni], acc[mi][ni], 0, 0, 0);
                acc[mi][ni] = __builtin_amdgcn_mfma_f32_16x16x32_bf16(fal[mi], fb[ni], acc[mi][ni], 0, 0, 0);
            }
    }

#pragma unroll
    for (int mi = 0; mi < 4; ++mi)
#pragma unroll
        for (int ni = 0; ni < 4; ++ni) {
            int n = bnBase + wc * 64 + ni * 16 + fr;
            float bv = bias[n];
#pragma unroll
            for (int r = 0; r < 4; ++r) {
                int m = bmBase + wr * 64 + mi * 16 + kg * 4 + r;
                int b_ = m >> 9, t_ = m & 511;           // m = b*512 + t
                Cout[(size_t)(t_ * BB + b_) * H3 + n] = f2bf_bits(acc[mi][ni][r] + bv);
            }
        }
}

// ---------------------------------------------------------------------------
// MFMA recurrent kernel. 256 blocks = 2 batch-domains x 128 unit-groups,
// 512 threads (8 waves = K-quadrants). Per block: w_hh slice (3 gates x 8
// units = 24 rows + 8 zero pad) read as FP32 and split hi/lo bf16 into
// swizzled LDS at kernel start (no global plane buffers -> workspace stays
// under the R1-R5 footprint; R6's +37.7MB overflowed d_ws and crashed).
// h exchanged as bf16 hi/lo planes via IC (sc0 sc1), double-buffered by step
// parity. 3-pass split MFMA (hh*wh + hl*wh + hh*wl) ~= fp32 accuracy.
#define RGRID 256

__global__ __launch_bounds__(512, 2) void gru_rec_mfma(
    const float* __restrict__ whh,                               // [3H][HD] fp32, layer base
    const float* __restrict__ bhh,                               // [3H]
    const u16*  __restrict__ gi,                                 // [T][B][3H]
    const float* __restrict__ h0,                                // [B][HD] layer base
    const u16* __restrict__ h0h, const u16* __restrict__ h0l,    // [B][HD] planes
    u16* __restrict__ hplh, u16* __restrict__ hpll,              // [2 parity][B][HD]
    u16* __restrict__ phi, u16* __restrict__ plo,                // next-layer planes or null
    float* __restrict__ seqout,                                  // [B][T][HD] or null
    float* __restrict__ hnout,                                   // [B][HD]
    unsigned* __restrict__ flags)                                // [2 dom][128]
{
    const int tid  = threadIdx.x;
    const int lane = tid & 63;
    const int w    = tid >> 6;          // 8 waves = K-quadrant (128 K each)
    const int ug   = blockIdx.x & 127;
    const int bg   = blockIdx.x >> 7;   // 0..1 batch domain
    const int n0   = ug * 8;
    const int b0   = bg * 16;

    unsigned* dom_flags = flags + bg * 128;

    __shared__ u16   wB[2][32][1024];   // 128KB swizzled: [plane][j=g*8+u (24)+pad][k]
    __shared__ float Cp[2][16][16];     // 2KB partial C [nt][mrow][col]
    __shared__ float hf[16][8];         // own fp32 h slice
    __shared__ float bsh[24];

    // ---- one-time: read fp32 w_hh slice, split hi/lo, store swizzled ----
    {
        int j   = tid >> 4;         // 0..31 (row)
        int c16 = tid & 15;         // 0..15
        int g = j >> 3, u = j & 7;
        const float* src = whh + (size_t)g * HD * HD + (size_t)(n0 + u) * HD;
#pragma unroll
        for (int c = 0; c < 8; ++c) {
            int ck = c16 + c * 16;              // 8-elem chunk index 0..127
            uint4 hi4 = {0, 0, 0, 0}, lo4 = {0, 0, 0, 0};
            if (j < 24) {
                f32x4 v0 = *(const f32x4*)(src + ck * 8);
                f32x4 v1 = *(const f32x4*)(src + ck * 8 + 4);
                unsigned hh[8], ll[8];
#pragma unroll
                for (int e = 0; e < 4; ++e) {
                    float f0 = v0[e];
                    hh[e] = f2bf_bits(f0);
                    ll[e] = f2bf_bits(f0 - bf_bits2f((u16)hh[e]));
                    float f1 = v1[e];
                    hh[4 + e] = f2bf_bits(f1);
                    ll[4 + e] = f2bf_bits(f1 - bf_bits2f((u16)hh[4 + e]));
                }
                hi4.x = hh[0] | (hh[1] << 16); hi4.y = hh[2] | (hh[3] << 16);
                hi4.z = hh[4] | (hh[5] << 16); hi4.w = hh[6] | (hh[7] << 16);
                lo4.x = ll[0] | (ll[1] << 16); lo4.y = ll[2] | (ll[3] << 16);
                lo4.z = ll[4] | (ll[5] << 16); lo4.w = ll[6] | (ll[7] << 16);
            }
            int swz = (ck * 16) ^ ((j & 7) << 4);   // byte offset in 2048B row
            *(uint4*)((char*)&wB[0][j][0] + swz) = hi4;
            *(uint4*)((char*)&wB[1][j][0] + swz) = lo4;
        }
    }
    if (tid < 24) bsh[tid] = bhh[(tid >> 3) * HD + n0 + (tid & 7)];
    if (tid < 128) hf[tid >> 3][tid & 7] = h0[(size_t)(b0 + (tid >> 3)) * HD + n0 + (tid & 7)];
    ((float*)Cp)[tid] = 0.f;     // zero all 512 Cp slots
    __syncthreads();

    // gi prefetch for t=0
    unsigned g0r = 0, g1r = 0, g2r = 0;
    if (tid < 128) {
        const u16* gp = gi + (size_t)(0 * BB + b0 + (tid >> 3)) * H3 + n0 + (tid & 7);
        ld_u16_async(g0r, gp);
        ld_u16_async(g1r, gp + HD);
        ld_u16_async(g2r, gp + 2 * HD);
    }

    const int arow = lane & 15, akg = lane >> 4;

    for (int t = 0; t < TT; ++t) {
        // ---- wave 0 polls own domain's 128 producer flags ----
        if (t > 0 && w == 0) {
            const unsigned* f1 = dom_flags + lane;
            const unsigned* f2 = dom_flags + 64 + lane;
            unsigned v1, v2;
            do {
                asm volatile("global_load_dword %0, %1, off sc0 sc1" : "=v"(v1) : "v"(f1));
                asm volatile("global_load_dword %0, %1, off sc0 sc1" : "=v"(v2) : "v"(f2));
                asm volatile("s_waitcnt vmcnt(0)" : "+v"(v1), "+v"(v2));
            } while (!__all((int)(v1 >= (unsigned)t && v2 >= (unsigned)t)));
        }
        __syncthreads();

        const u16* srcH = (t == 0) ? h0h : (hplh + (size_t)(t & 1) * BB * HD);
        const u16* srcL = (t == 0) ? h0l : (hpll + (size_t)(t & 1) * BB * HD);

        // ---- issue all 8 A-fragment loads (coherent, IC) ----
        i32x4 a[4][2];
#pragma unroll
        for (int kt = 0; kt < 4; ++kt) {
            int k0 = w * 128 + kt * 32 + akg * 8;
            const u16* ph = srcH + (size_t)(b0 + arow) * HD + k0;
            const u16* pl = srcL + (size_t)(b0 + arow) * HD + k0;
            asm volatile("global_load_dwordx4 %0, %1, off sc0 sc1" : "=v"(a[kt][0]) : "v"(ph));
            asm volatile("global_load_dwordx4 %0, %1, off sc0 sc1" : "=v"(a[kt][1]) : "v"(pl));
        }

        f32x4 acc[2] = {};
#pragma unroll
        for (int kt = 0; kt < 4; ++kt) {
            bf16x8 bw[2][2];
            int kbyte = (w * 128 + kt * 32) * 2 + akg * 16;
#pragma unroll
            for (int nt = 0; nt < 2; ++nt) {
                int j = nt * 16 + arow;
                int swz = kbyte ^ ((j & 7) << 4);
                bw[nt][0] = *(const bf16x8*)((const char*)&wB[0][j][0] + swz);
                bw[nt][1] = *(const bf16x8*)((const char*)&wB[1][j][0] + swz);
            }
            if (kt == 0)      asm volatile("s_waitcnt vmcnt(6)" : "+v"(a[0][0]), "+v"(a[0][1]));
            else if (kt == 1) asm volatile("s_waitcnt vmcnt(4)" : "+v"(a[1][0]), "+v"(a[1][1]));
            else if (kt == 2) asm volatile("s_waitcnt vmcnt(2)" : "+v"(a[2][0]), "+v"(a[2][1]));
            else              asm volatile("s_waitcnt vmcnt(0)" : "+v"(a[3][0]), "+v"(a[3][1]),
                                           "+v"(g0r), "+v"(g1r), "+v"(g2r));
            bf16x8 ahh = __builtin_bit_cast(bf16x8, a[kt][0]);
            bf16x8 ahl = __builtin_bit_cast(bf16x8, a[kt][1]);
#pragma unroll
            for (int nt = 0; nt < 2; ++nt) {
                acc[nt] = __builtin_amdgcn_mfma_f32_16x16x32_bf16(ahh, bw[nt][0], acc[nt], 0, 0, 0);
                acc[nt] = __builtin_amdgcn_mfma_f32_16x16x32_bf16(ahl, bw[nt][0], acc[nt], 0, 0, 0);
                acc[nt] = __builtin_amdgcn_mfma_f32_16x16x32_bf16(ahh, bw[nt][1], acc[nt], 0, 0, 0);
            }
        }
        // ---- reduce K-quadrants into Cp ----
#pragma unroll
        for (int nt = 0; nt < 2; ++nt)
#pragma unroll
            for (int i = 0; i < 4; ++i)
                atomicAdd(&Cp[nt][(lane >> 4) * 4 + i][lane & 15], acc[nt][i]);
        __syncthreads();

        // ---- gate phase: 128 threads, one (b,u) each ----
        if (tid < 128) {
            int r = tid >> 3, u = tid & 7;
            int b = b0 + r;
            float s0 = Cp[0][r][u], s1 = Cp[0][r][8 + u], s2 = Cp[1][r][u];
            Cp[0][r][u] = 0.f; Cp[0][r][8 + u] = 0.f; Cp[1][r][u] = 0.f;
            float dr = s0 + bsh[u], dz = s1 + bsh[8 + u], dn = s2 + bsh[16 + u];
            float ir  = bf_bits2f((u16)g0r);
            float iz  = bf_bits2f((u16)g1r);
            float inn = bf_bits2f((u16)g2r);
            float hp = hf[r][u];
            float rg = 1.f / (1.f + expf(-(ir + dr)));
            float zg = 1.f / (1.f + expf(-(iz + dz)));
            float ng = tanhf(inn + rg * dn);
            float hnew = (1.f - zg) * ng + zg * hp;
            hf[r][u] = hnew;
            u16 hb = f2bf_bits(hnew);
            u16 lb = f2bf_bits(hnew - bf_bits2f(hb));
            size_t pidx = (size_t)((t + 1) & 1) * BB * HD + (size_t)b * HD + n0 + u;
            coh_store_u16(hplh + pidx, (unsigned)hb);
            coh_store_u16(hpll + pidx, (unsigned)lb);
            size_t orow = ((size_t)b * TT + t) * HD + n0 + u;
            if (seqout) {
                seqout[orow] = hnew;
            } else {
                phi[orow] = hb;
                plo[orow] = lb;
            }
            if (t == TT - 1) hnout[(size_t)b * HD + n0 + u] = hnew;
            asm volatile("s_waitcnt vmcnt(0)" ::: "memory");   // drain releases
            if (t + 1 < TT) {
                const u16* gp = gi + (size_t)((t + 1) * BB + b) * H3 + n0 + u;
                ld_u16_async(g0r, gp);
                ld_u16_async(g1r, gp + HD);
                ld_u16_async(g2r, gp + 2 * HD);
            }
        }
        __syncthreads();
        if (t < TT - 1 && tid == 0) {
            unsigned* fp = dom_flags + ug;
            unsigned tv = (unsigned)(t + 1);
            asm volatile("global_store_dword %0, %1, off sc0 sc1" : : "v"(fp), "v"(tv) : "memory");
        }
    }
}

// ---------------------------------------------------------------------------
extern "C" void kernel_launch(void* const* d_in, const int* in_sizes, int n_in,
                              void* d_out, int out_size, void* d_ws, size_t ws_size,
                              hipStream_t stream) {
    const float* x   = (const float*)d_in[0];
    const float* h0  = (const float*)d_in[1];
    const float* wih = (const float*)d_in[2];
    const float* whh = (const float*)d_in[3];
    const float* bih = (const float*)d_in[4];
    const float* bhh = (const float*)d_in[5];
    float* out = (float*)d_out;

    char* ws = (char*)d_ws;
    size_t off = 0;
    auto alloc = [&](size_t bytes) -> void* {
        void* p = ws + off;
        off += (bytes + 255) & ~(size_t)255;
        return p;
    };
    // Total ~244.4 MB — same footprint class as R1-R5 (R6's +37.7MB of w_hh
    // plane buffers overflowed d_ws; those planes are now built in-kernel).
    u16* gi   = (u16*)alloc((size_t)MTOT * H3 * 2);        // 96 MB
    u16* p0h  = (u16*)alloc((size_t)MTOT * HD * 2);        // 32 MB
    u16* p0l  = (u16*)alloc((size_t)MTOT * HD * 2);
    u16* p1h  = (u16*)alloc((size_t)MTOT * HD * 2);
    u16* p1l  = (u16*)alloc((size_t)MTOT * HD * 2);
    u16* wihb = (u16*)alloc((size_t)LL * H3 * HD * 2);     // 18.9 MB
    u16* h0h  = (u16*)alloc((size_t)LL * BB * HD * 2);     // 196 KB
    u16* h0l  = (u16*)alloc((size_t)LL * BB * HD * 2);
    u16* hplh = (u16*)alloc((size_t)2 * BB * HD * 2);      // 128 KB parity planes
    u16* hpll = (u16*)alloc((size_t)2 * BB * HD * 2);
    unsigned* flags = (unsigned*)alloc(LL * 2 * 128 * 4);  // [L][2 dom][128]

    hipMemsetAsync(flags, 0, LL * 2 * 128 * 4, stream);

    split_f32_kernel<<<2048, 256, 0, stream>>>(x, p0h, p0l, MTOT * HD / 4);
    split_f32_kernel<<<64, 256, 0, stream>>>(h0, h0h, h0l, LL * BB * HD / 4);
    tobf_kernel<<<2048, 256, 0, stream>>>(wih, wihb, LL * H3 * HD / 4);

    float* seqbase = out;                        // [B][T][H]
    float* hnbase  = out + (size_t)BB * TT * HD; // [L][B][H]

    for (int l = 0; l < LL; ++l) {
        const u16* ah = (l == 1) ? p1h : p0h;
        const u16* al = (l == 1) ? p1l : p0l;
        gemm2p_kernel<<<dim3(128 * 24), 256, 0, stream>>>(
            ah, al, wihb + (size_t)l * H3 * HD, bih + (size_t)l * H3, gi);

        u16* oh = (l == 0) ? p1h : p0h;
        u16* ol = (l == 0) ? p1l : p0l;
        gru_rec_mfma<<<RGRID, 512, 0, stream>>>(
            whh + (size_t)l * H3 * HD,
            bhh + (size_t)l * H3, gi,
            h0 + (size_t)l * BB * HD,
            h0h + (size_t)l * BB * HD, h0l + (size_t)l * BB * HD,
            hplh, hpll,
            (l < 2) ? oh : (u16*)nullptr, (l < 2) ? ol : (u16*)nullptr,
            (l == 2) ? seqbase : (float*)nullptr,
            hnbase + (size_t)l * BB * HD,
            flags + (size_t)l * 2 * 128);
    }
}